// Round 1
// baseline (1457.655 us; speedup 1.0000x reference)
//
#include <hip/hip_runtime.h>
#include <math.h>

#define NTOT   65536
#define DDIM   256
#define BATCH  2048
#define NPREV  (NTOT - BATCH)   // 63488

#define QT 128
#define LT 128
#define KS 32
#define NTHREADS 256

#define NC_P 31
#define CHUNK_P 2048            // 31 * 2048 = 63488
#define NC_R 16
#define CHUNK_R 128             // 16 * 128 = 2048

#define INF_F 3.402823466e+38f

// ---------------- row norms of reached_lib ----------------
__global__ void lp_norms(const float* __restrict__ lib, float* __restrict__ ln) {
    const int row  = blockIdx.x * 4 + (threadIdx.x >> 6);
    const int lane = threadIdx.x & 63;
    const float4 v = reinterpret_cast<const float4*>(lib + (size_t)row * DDIM)[lane];
    float s = v.x * v.x + v.y * v.y + v.z * v.z + v.w * v.w;
#pragma unroll
    for (int off = 32; off > 0; off >>= 1) s += __shfl_down(s, off);
    if (lane == 0) ln[row] = s;
}

// ---------------- partial nearest-neighbor ----------------
// grid.x: query tiles (BATCH/QT), grid.y: lib chunks.
// score key = ln[l] - 2*dot(q,l)  (qn omitted: constant per query)
__global__ __launch_bounds__(NTHREADS, 3)
void lp_nn_partial(const float* __restrict__ Q, const float* __restrict__ L,
                   const float* __restrict__ ln, int chunkRows,
                   float* __restrict__ pscore, int* __restrict__ pidx, int nchunks)
{
    __shared__ float Qs[KS][QT];
    __shared__ float Ls[KS][LT];
    __shared__ float rk[NTHREADS * 8];
    __shared__ int   ri[NTHREADS * 8];

    const int t  = threadIdx.x;
    const int ty = t >> 4, tx = t & 15;
    const int q0 = ty * 8;
    const int qbase = blockIdx.x * QT;
    const int chunkBase = blockIdx.y * chunkRows;

    const int srow  = t & (QT - 1);
    const int shalf = t >> 7;

    float bkey[8]; int bidx[8];
#pragma unroll
    for (int j = 0; j < 8; ++j) { bkey[j] = INF_F; bidx[j] = 0x7fffffff; }

    for (int lt = 0; lt < chunkRows; lt += LT) {
        float acc[8][8];
#pragma unroll
        for (int j = 0; j < 8; ++j)
#pragma unroll
            for (int i = 0; i < 8; ++i) acc[j][i] = 0.f;

        for (int kb = 0; kb < DDIM; kb += KS) {
            __syncthreads();
            {
                const float* src = Q + (size_t)(qbase + srow) * DDIM + kb + shalf * 16;
#pragma unroll
                for (int c = 0; c < 4; ++c) {
                    const float4 v = *reinterpret_cast<const float4*>(src + c * 4);
                    const int kk = shalf * 16 + c * 4;
                    Qs[kk + 0][srow] = v.x; Qs[kk + 1][srow] = v.y;
                    Qs[kk + 2][srow] = v.z; Qs[kk + 3][srow] = v.w;
                }
                const float* srcL = L + (size_t)(chunkBase + lt + srow) * DDIM + kb + shalf * 16;
#pragma unroll
                for (int c = 0; c < 4; ++c) {
                    const float4 v = *reinterpret_cast<const float4*>(srcL + c * 4);
                    const int kk = shalf * 16 + c * 4;
                    Ls[kk + 0][srow] = v.x; Ls[kk + 1][srow] = v.y;
                    Ls[kk + 2][srow] = v.z; Ls[kk + 3][srow] = v.w;
                }
            }
            __syncthreads();
#pragma unroll
            for (int k = 0; k < KS; ++k) {
                const float4 qa = *reinterpret_cast<const float4*>(&Qs[k][q0]);
                const float4 qb = *reinterpret_cast<const float4*>(&Qs[k][q0 + 4]);
                const float4 la = *reinterpret_cast<const float4*>(&Ls[k][tx * 4]);
                const float4 lb = *reinterpret_cast<const float4*>(&Ls[k][64 + tx * 4]);
                const float qv[8] = {qa.x, qa.y, qa.z, qa.w, qb.x, qb.y, qb.z, qb.w};
                const float lv[8] = {la.x, la.y, la.z, la.w, lb.x, lb.y, lb.z, lb.w};
#pragma unroll
                for (int j = 0; j < 8; ++j)
#pragma unroll
                    for (int i = 0; i < 8; ++i)
                        acc[j][i] = fmaf(qv[j], lv[i], acc[j][i]);
            }
        }
        // fold this lib tile into the running best
#pragma unroll
        for (int i = 0; i < 8; ++i) {
            const int lrow = lt + ((i < 4) ? (tx * 4 + i) : (64 + tx * 4 + (i - 4)));
            const int gidx = chunkBase + lrow;
            const float lnv = ln[gidx];
#pragma unroll
            for (int j = 0; j < 8; ++j) {
                const float key = fmaf(-2.f, acc[j][i], lnv);
                if (key < bkey[j] || (key == bkey[j] && gidx < bidx[j])) {
                    bkey[j] = key; bidx[j] = gidx;
                }
            }
        }
    }

#pragma unroll
    for (int j = 0; j < 8; ++j) { rk[t * 8 + j] = bkey[j]; ri[t * 8 + j] = bidx[j]; }
    __syncthreads();
    if (tx == 0) {
#pragma unroll
        for (int j = 0; j < 8; ++j) {
            float bk = rk[(ty * 16) * 8 + j];
            int   bi = ri[(ty * 16) * 8 + j];
            for (int x = 1; x < 16; ++x) {
                const float k2 = rk[(ty * 16 + x) * 8 + j];
                const int   i2 = ri[(ty * 16 + x) * 8 + j];
                if (k2 < bk || (k2 == bk && i2 < bi)) { bk = k2; bi = i2; }
            }
            const int q = qbase + q0 + j;
            pscore[(size_t)q * nchunks + blockIdx.y] = bk;
            pidx  [(size_t)q * nchunks + blockIdx.y] = bi;
        }
    }
}

// ---------------- finalize: reduce partials, distances, value+grad ----------------
__global__ void lp_finalize(const float* __restrict__ Q,
                            const float* __restrict__ prevL,
                            const float* __restrict__ reachL,
                            const float* __restrict__ ps_p, const int* __restrict__ pi_p,
                            const float* __restrict__ ps_r, const int* __restrict__ pi_r,
                            float* __restrict__ out)
{
    const int q = blockIdx.x;
    const int lane = threadIdx.x;

    float k1 = (lane < NC_P) ? ps_p[(size_t)q * NC_P + lane] : INF_F;
    int   i1 = (lane < NC_P) ? pi_p[(size_t)q * NC_P + lane] : 0x7fffffff;
#pragma unroll
    for (int off = 32; off > 0; off >>= 1) {
        const float ok = __shfl_xor(k1, off);
        const int   oi = __shfl_xor(i1, off);
        if (ok < k1 || (ok == k1 && oi < i1)) { k1 = ok; i1 = oi; }
    }
    float k2 = (lane < NC_R) ? ps_r[(size_t)q * NC_R + lane] : INF_F;
    int   i2 = (lane < NC_R) ? pi_r[(size_t)q * NC_R + lane] : 0x7fffffff;
#pragma unroll
    for (int off = 32; off > 0; off >>= 1) {
        const float ok = __shfl_xor(k2, off);
        const int   oi = __shfl_xor(i2, off);
        if (ok < k2 || (ok == k2 && oi < i2)) { k2 = ok; i2 = oi; }
    }

    const float4 tv = reinterpret_cast<const float4*>(Q      + (size_t)q  * DDIM)[lane];
    const float4 e1 = reinterpret_cast<const float4*>(prevL  + (size_t)i1 * DDIM)[lane];
    const float4 e2 = reinterpret_cast<const float4*>(reachL + (size_t)i2 * DDIM)[lane];
    const float4 d1 = {tv.x - e1.x, tv.y - e1.y, tv.z - e1.z, tv.w - e1.w};
    const float4 d2 = {tv.x - e2.x, tv.y - e2.y, tv.z - e2.z, tv.w - e2.w};
    float s1 = d1.x * d1.x + d1.y * d1.y + d1.z * d1.z + d1.w * d1.w;
    float s2 = d2.x * d2.x + d2.y * d2.y + d2.z * d2.z + d2.w * d2.w;
#pragma unroll
    for (int off = 32; off > 0; off >>= 1) {
        s1 += __shfl_xor(s1, off);
        s2 += __shfl_xor(s2, off);
    }
    const float r1 = sqrtf(s1), r2 = sqrtf(s2);
    float4 g;
    g.x = d1.x / r1 - d2.x / r2;
    g.y = d1.y / r1 - d2.y / r2;
    g.z = d1.z / r1 - d2.z / r2;
    g.w = d1.w / r1 - d2.w / r2;
    reinterpret_cast<float4*>(out + BATCH + (size_t)q * DDIM)[lane] = g;
    if (lane == 0) out[q] = r1 - r2;
}

extern "C" void kernel_launch(void* const* d_in, const int* in_sizes, int n_in,
                              void* d_out, int out_size, void* d_ws, size_t ws_size,
                              hipStream_t stream) {
    const float* target_lib  = (const float*)d_in[0];
    const float* reached_lib = (const float*)d_in[1];
    const float* Qp     = target_lib  + (size_t)NPREV * DDIM;  // targets
    const float* prevL  = reached_lib;                          // prev
    const float* reachL = reached_lib + (size_t)NPREV * DDIM;  // reached

    float* ws     = (float*)d_ws;
    float* ln_all = ws;                          // NTOT floats
    float* ps_p   = ln_all + NTOT;               // BATCH*NC_P
    float* ps_r   = ps_p + (size_t)BATCH * NC_P; // BATCH*NC_R
    int*   pi_p   = (int*)(ps_r + (size_t)BATCH * NC_R);
    int*   pi_r   = pi_p + (size_t)BATCH * NC_P;
    float* out    = (float*)d_out;

    lp_norms<<<NTOT / 4, 256, 0, stream>>>(reached_lib, ln_all);
    lp_nn_partial<<<dim3(BATCH / QT, NC_P), NTHREADS, 0, stream>>>(
        Qp, prevL, ln_all, CHUNK_P, ps_p, pi_p, NC_P);
    lp_nn_partial<<<dim3(BATCH / QT, NC_R), NTHREADS, 0, stream>>>(
        Qp, reachL, ln_all + NPREV, CHUNK_R, ps_r, pi_r, NC_R);
    lp_finalize<<<BATCH, 64, 0, stream>>>(Qp, prevL, reachL, ps_p, pi_p, ps_r, pi_r, out);
}

// Round 3
// 318.335 us; speedup vs baseline: 4.5790x; 4.5790x over previous
//
#include <hip/hip_runtime.h>
#include <math.h>

#define NTOT   65536
#define DDIM   256
#define BATCH  2048
#define NPREV  (NTOT - BATCH)   // 63488

#define NC_P 31
#define CHUNK_P 2048            // 31 * 2048 = 63488
#define NC_R 16
#define CHUNK_R 128             // 16 * 128 = 2048

#define INF_F 3.402823466e+38f

typedef float  f32x4 __attribute__((ext_vector_type(4)));
typedef _Float16 half8 __attribute__((ext_vector_type(8)));

// ---------------- row norms of reached_lib (original fp32 data) ----------------
__global__ void lp_norms(const float* __restrict__ lib, float* __restrict__ ln) {
    const int row  = blockIdx.x * 4 + (threadIdx.x >> 6);
    const int lane = threadIdx.x & 63;
    const float4 v = reinterpret_cast<const float4*>(lib + (size_t)row * DDIM)[lane];
    float s = v.x * v.x + v.y * v.y + v.z * v.z + v.w * v.w;
#pragma unroll
    for (int off = 32; off > 0; off >>= 1) s += __shfl_down(s, off);
    if (lane == 0) ln[row] = s;
}

// fp16 split with x256 scaling (keeps residual out of subnormal range)
__device__ __forceinline__ void cvt_split(const f32x4 a, const f32x4 b,
                                          half8& h, half8& l) {
    float v[8] = {a[0], a[1], a[2], a[3], b[0], b[1], b[2], b[3]};
#pragma unroll
    for (int j = 0; j < 8; ++j) {
        const float s = v[j] * 256.0f;
        const _Float16 hh = (_Float16)s;
        const _Float16 ll = (_Float16)(s - (float)hh);
        h[j] = hh; l[j] = ll;
    }
}

// ---------------- MFMA nearest-neighbor partial ----------------
// grid.x: query tiles (BATCH/128), grid.y: lib chunks
// score key (scaled by 2^16) = 65536*ln[l] - 2*acc,  acc = 65536*dot(q,l)
__global__ __launch_bounds__(256, 2)
void lp_nn_mfma(const float* __restrict__ Q, const float* __restrict__ L,
                const float* __restrict__ ln, int chunkRows,
                float* __restrict__ pscore, int* __restrict__ pidx, int nchunks)
{
    __shared__ _Float16 Ah[128 * 32];
    __shared__ _Float16 Al[128 * 32];
    __shared__ _Float16 Bh[128 * 32];
    __shared__ _Float16 Bl[128 * 32];
    __shared__ float xk[2][128];
    __shared__ int   xi[2][128];

    const int t    = threadIdx.x;
    const int wid  = t >> 6, lane = t & 63;
    const int wq   = wid >> 1, wl = wid & 1;      // wave tile: (wq*64, wl*64)
    const int col  = lane & 15, rg = lane >> 4;   // C: col = lane&15, row = rg*4+i
    const int qbase = blockIdx.x * 128;
    const int chunkBase = blockIdx.y * chunkRows;

    // staging assignment: 4 lanes per row, 8 fp32 (32B) per thread per row-pass
    const int srow   = t >> 2;   // 0..63
    const int schunk = t & 3;    // 16B slot (8 halves) pre-swizzle

    float bkey[4][4];
    int   bidxr[4][4];
#pragma unroll
    for (int mf = 0; mf < 4; ++mf)
#pragma unroll
        for (int i = 0; i < 4; ++i) { bkey[mf][i] = INF_F; bidxr[mf][i] = 0x7fffffff; }

    for (int lt = 0; lt < chunkRows; lt += 128) {
        f32x4 acc[4][4];
#pragma unroll
        for (int mf = 0; mf < 4; ++mf)
#pragma unroll
            for (int nf = 0; nf < 4; ++nf) acc[mf][nf] = (f32x4)(0.f);

        for (int kb = 0; kb < DDIM; kb += 32) {
            __syncthreads();
#pragma unroll
            for (int sr = 0; sr < 2; ++sr) {
                const int r = srow + 64 * sr;
                const int s = schunk ^ (r & 3) ^ ((r >> 2) & 3);
                // Q rows
                {
                    const float* src = Q + (size_t)(qbase + r) * DDIM + kb + schunk * 8;
                    const f32x4 a = *reinterpret_cast<const f32x4*>(src);
                    const f32x4 b = *reinterpret_cast<const f32x4*>(src + 4);
                    half8 h, l; cvt_split(a, b, h, l);
                    *reinterpret_cast<half8*>(&Ah[r * 32 + s * 8]) = h;
                    *reinterpret_cast<half8*>(&Al[r * 32 + s * 8]) = l;
                }
                // L rows
                {
                    const float* src = L + (size_t)(chunkBase + lt + r) * DDIM + kb + schunk * 8;
                    const f32x4 a = *reinterpret_cast<const f32x4*>(src);
                    const f32x4 b = *reinterpret_cast<const f32x4*>(src + 4);
                    half8 h, l; cvt_split(a, b, h, l);
                    *reinterpret_cast<half8*>(&Bh[r * 32 + s * 8]) = h;
                    *reinterpret_cast<half8*>(&Bl[r * 32 + s * 8]) = l;
                }
            }
            __syncthreads();

            half8 ah[4], al[4];
#pragma unroll
            for (int mf = 0; mf < 4; ++mf) {
                const int r = wq * 64 + mf * 16 + col;
                const int s = rg ^ (r & 3) ^ ((r >> 2) & 3);
                ah[mf] = *reinterpret_cast<const half8*>(&Ah[r * 32 + s * 8]);
                al[mf] = *reinterpret_cast<const half8*>(&Al[r * 32 + s * 8]);
            }
#pragma unroll
            for (int nf = 0; nf < 4; ++nf) {
                const int r = wl * 64 + nf * 16 + col;
                const int s = rg ^ (r & 3) ^ ((r >> 2) & 3);
                const half8 bh = *reinterpret_cast<const half8*>(&Bh[r * 32 + s * 8]);
                const half8 bl = *reinterpret_cast<const half8*>(&Bl[r * 32 + s * 8]);
#pragma unroll
                for (int mf = 0; mf < 4; ++mf) {
                    acc[mf][nf] = __builtin_amdgcn_mfma_f32_16x16x32_f16(ah[mf], bh, acc[mf][nf], 0, 0, 0);
                    acc[mf][nf] = __builtin_amdgcn_mfma_f32_16x16x32_f16(ah[mf], bl, acc[mf][nf], 0, 0, 0);
                    acc[mf][nf] = __builtin_amdgcn_mfma_f32_16x16x32_f16(al[mf], bh, acc[mf][nf], 0, 0, 0);
                }
            }
        }

        // fold this 128-row lib tile into the running best
#pragma unroll
        for (int nf = 0; nf < 4; ++nf) {
            const int gidx = chunkBase + lt + wl * 64 + nf * 16 + col;
            const float lnv = ln[gidx] * 65536.0f;
#pragma unroll
            for (int mf = 0; mf < 4; ++mf)
#pragma unroll
                for (int i = 0; i < 4; ++i) {
                    const float key = fmaf(-2.f, acc[mf][nf][i], lnv);
                    if (key < bkey[mf][i] || (key == bkey[mf][i] && gidx < bidxr[mf][i])) {
                        bkey[mf][i] = key; bidxr[mf][i] = gidx;
                    }
                }
        }
    }

    // butterfly-reduce across the 16 C-columns (low 4 lane bits)
#pragma unroll
    for (int off = 1; off < 16; off <<= 1) {
#pragma unroll
        for (int mf = 0; mf < 4; ++mf)
#pragma unroll
            for (int i = 0; i < 4; ++i) {
                const float ok = __shfl_xor(bkey[mf][i], off);
                const int   oi = __shfl_xor(bidxr[mf][i], off);
                if (ok < bkey[mf][i] || (ok == bkey[mf][i] && oi < bidxr[mf][i])) {
                    bkey[mf][i] = ok; bidxr[mf][i] = oi;
                }
            }
    }
    // cross-wave combine: waves (wq,0) and (wq,1) cover the same q-rows
    // over different lib-column halves -> reduce via LDS, single writer per q.
    if (col == 0) {
#pragma unroll
        for (int mf = 0; mf < 4; ++mf)
#pragma unroll
            for (int i = 0; i < 4; ++i) {
                const int ql = wq * 64 + mf * 16 + rg * 4 + i;
                xk[wl][ql] = bkey[mf][i];
                xi[wl][ql] = bidxr[mf][i];
            }
    }
    __syncthreads();
    if (t < 128) {
        float bk = xk[0][t]; int bi = xi[0][t];
        const float k2 = xk[1][t]; const int i2 = xi[1][t];
        if (k2 < bk || (k2 == bk && i2 < bi)) { bk = k2; bi = i2; }
        const int q = qbase + t;
        pscore[(size_t)q * nchunks + blockIdx.y] = bk;
        pidx  [(size_t)q * nchunks + blockIdx.y] = bi;
    }
}

// ---------------- finalize: reduce partials, exact distances, value+grad ----------------
__global__ void lp_finalize(const float* __restrict__ Q,
                            const float* __restrict__ prevL,
                            const float* __restrict__ reachL,
                            const float* __restrict__ ps_p, const int* __restrict__ pi_p,
                            const float* __restrict__ ps_r, const int* __restrict__ pi_r,
                            float* __restrict__ out)
{
    const int q = blockIdx.x;
    const int lane = threadIdx.x;

    float k1 = (lane < NC_P) ? ps_p[(size_t)q * NC_P + lane] : INF_F;
    int   i1 = (lane < NC_P) ? pi_p[(size_t)q * NC_P + lane] : 0x7fffffff;
#pragma unroll
    for (int off = 32; off > 0; off >>= 1) {
        const float ok = __shfl_xor(k1, off);
        const int   oi = __shfl_xor(i1, off);
        if (ok < k1 || (ok == k1 && oi < i1)) { k1 = ok; i1 = oi; }
    }
    float k2 = (lane < NC_R) ? ps_r[(size_t)q * NC_R + lane] : INF_F;
    int   i2 = (lane < NC_R) ? pi_r[(size_t)q * NC_R + lane] : 0x7fffffff;
#pragma unroll
    for (int off = 32; off > 0; off >>= 1) {
        const float ok = __shfl_xor(k2, off);
        const int   oi = __shfl_xor(i2, off);
        if (ok < k2 || (ok == k2 && oi < i2)) { k2 = ok; i2 = oi; }
    }

    const float4 tv = reinterpret_cast<const float4*>(Q      + (size_t)q  * DDIM)[lane];
    const float4 e1 = reinterpret_cast<const float4*>(prevL  + (size_t)i1 * DDIM)[lane];
    const float4 e2 = reinterpret_cast<const float4*>(reachL + (size_t)i2 * DDIM)[lane];
    const float4 d1 = {tv.x - e1.x, tv.y - e1.y, tv.z - e1.z, tv.w - e1.w};
    const float4 d2 = {tv.x - e2.x, tv.y - e2.y, tv.z - e2.z, tv.w - e2.w};
    float s1 = d1.x * d1.x + d1.y * d1.y + d1.z * d1.z + d1.w * d1.w;
    float s2 = d2.x * d2.x + d2.y * d2.y + d2.z * d2.z + d2.w * d2.w;
#pragma unroll
    for (int off = 32; off > 0; off >>= 1) {
        s1 += __shfl_xor(s1, off);
        s2 += __shfl_xor(s2, off);
    }
    const float r1 = sqrtf(s1), r2 = sqrtf(s2);
    float4 g;
    g.x = d1.x / r1 - d2.x / r2;
    g.y = d1.y / r1 - d2.y / r2;
    g.z = d1.z / r1 - d2.z / r2;
    g.w = d1.w / r1 - d2.w / r2;
    reinterpret_cast<float4*>(out + BATCH + (size_t)q * DDIM)[lane] = g;
    if (lane == 0) out[q] = r1 - r2;
}

extern "C" void kernel_launch(void* const* d_in, const int* in_sizes, int n_in,
                              void* d_out, int out_size, void* d_ws, size_t ws_size,
                              hipStream_t stream) {
    const float* target_lib  = (const float*)d_in[0];
    const float* reached_lib = (const float*)d_in[1];
    const float* Qp     = target_lib  + (size_t)NPREV * DDIM;  // targets
    const float* prevL  = reached_lib;                          // prev
    const float* reachL = reached_lib + (size_t)NPREV * DDIM;  // reached

    float* ws     = (float*)d_ws;
    float* ln_all = ws;                          // NTOT floats
    float* ps_p   = ln_all + NTOT;               // BATCH*NC_P
    float* ps_r   = ps_p + (size_t)BATCH * NC_P; // BATCH*NC_R
    int*   pi_p   = (int*)(ps_r + (size_t)BATCH * NC_R);
    int*   pi_r   = pi_p + (size_t)BATCH * NC_P;
    float* out    = (float*)d_out;

    lp_norms<<<NTOT / 4, 256, 0, stream>>>(reached_lib, ln_all);
    lp_nn_mfma<<<dim3(BATCH / 128, NC_P), 256, 0, stream>>>(
        Qp, prevL, ln_all, CHUNK_P, ps_p, pi_p, NC_P);
    lp_nn_mfma<<<dim3(BATCH / 128, NC_R), 256, 0, stream>>>(
        Qp, reachL, ln_all + NPREV, CHUNK_R, ps_r, pi_r, NC_R);
    lp_finalize<<<BATCH, 64, 0, stream>>>(Qp, prevL, reachL, ps_p, pi_p, ps_r, pi_r, out);
}